// Round 5
// baseline (411.407 us; speedup 1.0000x reference)
//
#include <hip/hip_runtime.h>
#include <hip/hip_bf16.h>

#define H 16
#define S 2048
#define D 64
#define BM 64            // q-rows per block (16 per wave)
#define BN 64            // t per tile
#define NT (S / BN)      // 32 tiles

typedef __attribute__((ext_vector_type(8))) short bf16x8;
typedef __attribute__((ext_vector_type(4))) float fx4;
typedef __attribute__((ext_vector_type(4))) unsigned uintx4;
typedef __attribute__((ext_vector_type(2))) unsigned uintx2;

// fp32 -> bf16 bits, round-to-nearest-even (scalar)
static __device__ __forceinline__ short f2bf(float x) {
    unsigned u = __float_as_uint(x);
    u += 0x7fffu + ((u >> 16) & 1u);
    return (short)(u >> 16);
}
static __device__ __forceinline__ float bf2f(short s) {
    return __uint_as_float(((unsigned)(unsigned short)s) << 16);
}
// packed fp32x2 -> bf16x2 (RNE), low short = a
static __device__ __forceinline__ unsigned pkbf(float a, float b) {
    union { __hip_bfloat162 h; unsigned u; } c;
    c.h = __float22bfloat162_rn(make_float2(a, b));
    return c.u;
}

// LDS layout: granule-major (16B granules), phys_granule = f ^ ((f>>3)&7).
// K/VT logical granule: f = (tn16*2 + kt)*64 + quad*16 + col
//   Kh/Kl: holds K[t=tn16*16+col][d=kt*32+quad*8+j]   (B-frag for QK)
//   VT   : holds V[t=kt*32+quad*8+j][d=nt*16+col]     (B-frag for PV)
// P (per wave, 128 granules): f = wave*128 + kt*64 + quad*16 + col
//   holds P[row=col][t=kt*32+quad*8+j]                (A-frag for PV)
// Reads: f = base(mult of 64) + lane  ->  addr = base*512B + lswz*16B (immediates!)

__global__ __launch_bounds__(256)
void ParallelRetention_origin_25374666785438_kernel(
    const float* __restrict__ q, const float* __restrict__ k,
    const float* __restrict__ v, const float* __restrict__ om,
    float* __restrict__ out)
{
    __shared__ __align__(16) short ldsKh[2][4096];
    __shared__ __align__(16) short ldsKl[2][4096];
    __shared__ __align__(16) short ldsVT[2][4096];
    __shared__ __align__(16) short ldsP[4096];      // 57344 B total

    const int tid  = threadIdx.x;
    const int wave = tid >> 6;
    const int lane = tid & 63;
    const int col  = lane & 15;
    const int quad = lane >> 4;
    const int ls8  = (lane ^ ((lane >> 3) & 7)) << 3;   // swizzled lane granule, in shorts

    // ---- K staging mapping: thread owns row krow, d-chunk ksub*16..+15 ----
    const int krow = tid >> 2;
    const int ksub = tid & 3;
    const int kfA  = ((krow >> 4) * 2 + (ksub >> 1)) * 64 + ((ksub & 1) * 2) * 16 + (krow & 15);
    const int kwA  = (kfA ^ ((kfA >> 3) & 7)) << 3;
    const int kfB  = kfA + 16;
    const int kwB  = (kfB ^ ((kfB >> 3) & 7)) << 3;

    // ---- V staging mapping: thread owns t_base..+3 x d4..+3 ----
    const int t_base = (tid >> 4) << 2;
    const int d4     = (tid & 15) << 2;
    int vtw[4];
#pragma unroll
    for (int dd = 0; dd < 4; ++dd) {
        int d = d4 + dd;
        int f = ((d >> 4) * 2 + (t_base >> 5)) * 64 + ((t_base >> 3) & 3) * 16 + (d & 15);
        vtw[dd] = ((f ^ ((f >> 3) & 7)) << 3) + (t_base & 7);
    }

    // ---- P write lane constants (xor-swizzled scalar b16 writes) ----
    const int Cc = ((col >> 3) << 1) + (quad >> 1);
    int C8[4];
#pragma unroll
    for (int r = 0; r < 4; ++r) C8[r] = (r ^ Cc) << 3;
    const int pbase = wave * 1024 + (col >> 3) * 128 + quad * 32 + (col & 7);
    const int pb0 = pbase, pb1 = pbase ^ 32;

    const int h  = blockIdx.x & 15;      // consecutive blocks -> different heads
    const int qb = blockIdx.x >> 4;
    const int row0 = qb * BM;

    const size_t headQK = (size_t)h * S * D;
    const size_t headM  = (size_t)h * S * S;

    // ---- Q A-fragments once, hi/lo split ----
    bf16x8 qh[2], qlo[2];
    {
        const int s_row = row0 + wave * 16 + col;
        const float* qp = q + headQK + (size_t)s_row * D + quad * 8;
#pragma unroll
        for (int c = 0; c < 2; ++c) {
            fx4 a = *(const fx4*)(qp + c * 32);
            fx4 b = *(const fx4*)(qp + c * 32 + 4);
            float f[8] = {a[0],a[1],a[2],a[3],b[0],b[1],b[2],b[3]};
#pragma unroll
            for (int j = 0; j < 8; ++j) {
                short hi = f2bf(f[j]);
                qh[c][j]  = hi;
                qlo[c][j] = f2bf(f[j] - bf2f(hi));
            }
        }
    }

    fx4 U[4];
#pragma unroll
    for (int nt = 0; nt < 4; ++nt) { U[nt][0]=0.f; U[nt][1]=0.f; U[nt][2]=0.f; U[nt][3]=0.f; }
    float rs_acc[4] = {0.f, 0.f, 0.f, 0.f};
    float T_acc[4]  = {0.f, 0.f, 0.f, 0.f};
    float om0[16], om1[16];

    const float* kbase0 = k + headQK;
    const float* vbase0 = v + headQK;
    const float* ombase = om + headM + (size_t)(row0 + wave * 16) * S;

    auto load_kv = [&](int t0, fx4 (&kr)[4], fx4 (&vr)[4]) {
        const float* kb = kbase0 + (size_t)t0 * D + (size_t)krow * D + ksub * 16;
        const float* vb = vbase0 + (size_t)t0 * D;
#pragma unroll
        for (int i = 0; i < 4; ++i) kr[i] = *(const fx4*)(kb + i * 4);
#pragma unroll
        for (int r = 0; r < 4; ++r) vr[r] = *(const fx4*)(vb + (size_t)(t_base + r) * D + d4);
    };
    auto load_om = [&](int t0, float (&o)[16]) {
        const float* omp = ombase + t0;
#pragma unroll
        for (int tn = 0; tn < 4; ++tn)
#pragma unroll
            for (int r = 0; r < 4; ++r)
                o[tn * 4 + r] = omp[(size_t)(quad * 4 + r) * S + tn * 16 + col];
    };
    auto stage_write = [&](const fx4 (&kr)[4], const fx4 (&vr)[4], int buf) {
        float kf[16];
#pragma unroll
        for (int i = 0; i < 4; ++i) {
            kf[i*4+0]=kr[i][0]; kf[i*4+1]=kr[i][1]; kf[i*4+2]=kr[i][2]; kf[i*4+3]=kr[i][3];
        }
        unsigned hh[8], ll[8];
#pragma unroll
        for (int p = 0; p < 8; ++p) {
            float a = kf[2*p], b = kf[2*p+1];
            unsigned u = pkbf(a, b);
            hh[p] = u;
            float la = a - __uint_as_float(u << 16);
            float lb = b - __uint_as_float(u & 0xffff0000u);
            ll[p] = pkbf(la, lb);
        }
        *(uintx4*)(&ldsKh[buf][kwA]) = uintx4{hh[0], hh[1], hh[2], hh[3]};
        *(uintx4*)(&ldsKh[buf][kwB]) = uintx4{hh[4], hh[5], hh[6], hh[7]};
        *(uintx4*)(&ldsKl[buf][kwA]) = uintx4{ll[0], ll[1], ll[2], ll[3]};
        *(uintx4*)(&ldsKl[buf][kwB]) = uintx4{ll[4], ll[5], ll[6], ll[7]};
#pragma unroll
        for (int dd = 0; dd < 4; ++dd) {
            unsigned p0 = pkbf(vr[0][dd], vr[1][dd]);
            unsigned p1 = pkbf(vr[2][dd], vr[3][dd]);
            *(uintx2*)(&ldsVT[buf][vtw[dd]]) = uintx2{p0, p1};
        }
    };
    auto compute = [&](int buf, const float (&omc)[16]) {
        const short* Kh = ldsKh[buf];
        const short* Kl = ldsKl[buf];
        const short* VT = ldsVT[buf];
#pragma unroll
        for (int tn = 0; tn < 4; ++tn) {
            bf16x8 kh0 = *(const bf16x8*)(&Kh[(tn*2+0)*512 + ls8]);
            bf16x8 kh1 = *(const bf16x8*)(&Kh[(tn*2+1)*512 + ls8]);
            bf16x8 kl0 = *(const bf16x8*)(&Kl[(tn*2+0)*512 + ls8]);
            bf16x8 kl1 = *(const bf16x8*)(&Kl[(tn*2+1)*512 + ls8]);
            fx4 z; z[0]=0.f; z[1]=0.f; z[2]=0.f; z[3]=0.f;
            z = __builtin_amdgcn_mfma_f32_16x16x32_bf16(qh[0],  kh0, z, 0, 0, 0);
            z = __builtin_amdgcn_mfma_f32_16x16x32_bf16(qh[1],  kh1, z, 0, 0, 0);
            z = __builtin_amdgcn_mfma_f32_16x16x32_bf16(qh[0],  kl0, z, 0, 0, 0);
            z = __builtin_amdgcn_mfma_f32_16x16x32_bf16(qh[1],  kl1, z, 0, 0, 0);
            z = __builtin_amdgcn_mfma_f32_16x16x32_bf16(qlo[0], kh0, z, 0, 0, 0);
            z = __builtin_amdgcn_mfma_f32_16x16x32_bf16(qlo[1], kh1, z, 0, 0, 0);
            const int pa = ((tn & 1) ? pb1 : pb0) + (tn >> 1) * 512 + (tn & 1) * 256;
#pragma unroll
            for (int r = 0; r < 4; ++r) {
                float m = omc[tn * 4 + r];
                float p = z[r] * m;
                rs_acc[r] += m;
                T_acc[r]  += p;
                ldsP[pa + C8[r]] = f2bf(p);
            }
        }
#pragma unroll
        for (int kt = 0; kt < 2; ++kt) {
            bf16x8 paf = *(const bf16x8*)(&ldsP[wave*1024 + kt*512 + ls8]);
#pragma unroll
            for (int nt = 0; nt < 4; ++nt) {
                bf16x8 vb = *(const bf16x8*)(&VT[(nt*2+kt)*512 + ls8]);
                U[nt] = __builtin_amdgcn_mfma_f32_16x16x32_bf16(paf, vb, U[nt], 0, 0, 0);
            }
        }
    };

    // ---- prologue ----
    {
        fx4 kr[4], vr[4];
        load_kv(0, kr, vr);
        load_om(0, om0);
        stage_write(kr, vr, 0);
    }

    // ---- pipelined main loop ----
    for (int it2 = 0; it2 < NT; it2 += 2) {
        {
            __syncthreads();
            fx4 kr[4], vr[4];
            load_kv((it2 + 1) * BN, kr, vr);
            load_om((it2 + 1) * BN, om1);
            compute(0, om0);
            stage_write(kr, vr, 1);
        }
        {
            __syncthreads();
            const bool pf = (it2 + 2 < NT);
            fx4 kr[4], vr[4];
            if (pf) {
                load_kv((it2 + 2) * BN, kr, vr);
                load_om((it2 + 2) * BN, om0);
            }
            compute(1, om1);
            if (pf) stage_write(kr, vr, 0);
        }
    }

    // ---- epilogue ----
#pragma unroll
    for (int off = 1; off < 16; off <<= 1) {
#pragma unroll
        for (int r = 0; r < 4; ++r) {
            rs_acc[r] += __shfl_xor(rs_acc[r], off, 64);
            T_acc[r]  += __shfl_xor(T_acc[r], off, 64);
        }
    }
    float factor[4];
#pragma unroll
    for (int r = 0; r < 4; ++r) {
        float rs  = rs_acc[r];
        float inv = rs > 0.f ? rsqrtf(rs) : 0.f;
        float rowsum = T_acc[r] * inv;
        float sc = fabsf(rowsum);
        sc = sc < 1.f ? 1.f : sc;
        factor[r] = inv / sc;
    }
    float* op = out + headQK + (size_t)(row0 + wave * 16) * D;
#pragma unroll
    for (int r = 0; r < 4; ++r)
#pragma unroll
        for (int nt = 0; nt < 4; ++nt)
            op[(size_t)(quad * 4 + r) * D + nt * 16 + col] = U[nt][r] * factor[r];
}

extern "C" void kernel_launch(void* const* d_in, const int* in_sizes, int n_in,
                              void* d_out, int out_size, void* d_ws, size_t ws_size,
                              hipStream_t stream) {
    const float* q  = (const float*)d_in[0];
    const float* k  = (const float*)d_in[1];
    const float* v  = (const float*)d_in[2];
    const float* om = (const float*)d_in[3];
    float* out = (float*)d_out;
    (void)in_sizes; (void)n_in; (void)out_size; (void)d_ws; (void)ws_size;

    dim3 grid(H * (S / BM));   // 512 blocks
    dim3 block(256);
    hipLaunchKernelGGL(ParallelRetention_origin_25374666785438_kernel,
                       grid, block, 0, stream, q, k, v, om, out);
}